// Round 14
// baseline (66.838 us; speedup 1.0000x reference)
//
#include <hip/hip_runtime.h>
#include <math.h>

constexpr int B = 8, S = 1024, D = 256, H = 8, HD = 32;

typedef __attribute__((ext_vector_type(8))) short bf16x8;
typedef __attribute__((ext_vector_type(16))) float f32x16;
typedef __attribute__((ext_vector_type(2)))  int  int2v;

__device__ __forceinline__ uint cvtpk(float a, float b) {
    uint r;
    asm("v_cvt_pk_bf16_f32 %0, %1, %2" : "=v"(r) : "v"(a), "v"(b));
    return r;
}
__device__ __forceinline__ float xswap32f(float v, int hi) {
    int2v t = __builtin_amdgcn_permlane32_swap(__float_as_int(v), __float_as_int(v), false, false);
    return __int_as_float(hi ? t[0] : t[1]);
}

// ---------------------------------------------------------------------------
// K1: fused MFMA projection (R9 form).
// ---------------------------------------------------------------------------
__global__ __launch_bounds__(512, 4) void proj_mfma(
    const float* __restrict__ query, const float* __restrict__ key_,
    const float* __restrict__ value,
    const float* __restrict__ Wq, const float* __restrict__ Wk,
    const float* __restrict__ Wv,
    const float* __restrict__ bq, const float* __restrict__ bk,
    const float* __restrict__ bv, float qscale,
    ushort* __restrict__ qbuf, ushort* __restrict__ kbuf,
    ushort* __restrict__ vtbuf, float* __restrict__ cpart)
{
    __shared__ ushort xf[8192];
    __shared__ float bias_lds[256];

    const int m = blockIdx.y;
    const int tid = threadIdx.x;
    const int w = tid >> 6, lane = tid & 63;
    const int l31 = lane & 31, hi = lane >> 5;
    const int h = w;

    const float* xsrc = (m == 0) ? query : (m == 1) ? key_ : value;
    const float* Wsrc = (m == 0) ? Wq : (m == 1) ? Wk : Wv;
    const float* bsrc = (m == 0) ? bq : (m == 1) ? bk : bv;
    ushort* yb = (m == 0) ? qbuf : (m == 1) ? kbuf : vtbuf;
    const float wscale = (m == 0) ? qscale : 1.0f;

    if (tid < 256) bias_lds[tid] = bsrc[tid] * wscale;

    bf16x8 wf[16];
    {
        const float* wrow = Wsrc + ((size_t)(h * 32 + l31)) * 256 + hi * 8;
        #pragma unroll
        for (int kc = 0; kc < 16; ++kc) {
            float4 a = *(const float4*)(wrow + kc * 16);
            float4 b = *(const float4*)(wrow + kc * 16 + 4);
            uint4 p;
            p.x = cvtpk(a.x * wscale, a.y * wscale);
            p.y = cvtpk(a.z * wscale, a.w * wscale);
            p.z = cvtpk(b.x * wscale, b.y * wscale);
            p.w = cvtpk(b.z * wscale, b.w * wscale);
            wf[kc] = __builtin_bit_cast(bf16x8, p);
        }
    }

    const int sst = tid & 31, skc = tid >> 5;
    float cpacc = 0.f;

    for (int it = 0; it < 2; ++it) {
        const int stile = blockIdx.x * 2 + it;
        const int b_ = stile >> 5, t32 = stile & 31;

        __syncthreads();
        {
            const float* xrow = xsrc + ((size_t)(stile * 32 + sst)) * 256 + skc * 16;
            float4 a0 = *(const float4*)(xrow + 0);
            float4 a1 = *(const float4*)(xrow + 4);
            float4 a2 = *(const float4*)(xrow + 8);
            float4 a3 = *(const float4*)(xrow + 12);
            uint2 w01 = { cvtpk(a0.x, a0.y), cvtpk(a0.z, a0.w) };
            uint2 w23 = { cvtpk(a1.x, a1.y), cvtpk(a1.z, a1.w) };
            uint2 w45 = { cvtpk(a2.x, a2.y), cvtpk(a2.z, a2.w) };
            uint2 w67 = { cvtpk(a3.x, a3.y), cvtpk(a3.z, a3.w) };
            ushort* base = xf + skc * 512 + sst * 4;
            *(uint2*)(base +   0) = w01;
            *(uint2*)(base + 128) = w23;
            *(uint2*)(base + 256) = w45;
            *(uint2*)(base + 384) = w67;
        }
        __syncthreads();

        f32x16 acc;
        #pragma unroll
        for (int r = 0; r < 16; ++r) acc[r] = 0.f;
        #pragma unroll
        for (int kc = 0; kc < 16; ++kc) {
            const ushort* rb = xf + kc * 512 + hi * 256 + l31 * 4;
            uint2 lo = *(const uint2*)rb;
            uint2 hj = *(const uint2*)(rb + 128);
            uint4 xw = { lo.x, lo.y, hj.x, hj.y };
            bf16x8 xfrag = __builtin_bit_cast(bf16x8, xw);
            if (m < 2)
                acc = __builtin_amdgcn_mfma_f32_32x32x16_bf16(wf[kc], xfrag, acc, 0, 0, 0);
            else
                acc = __builtin_amdgcn_mfma_f32_32x32x16_bf16(xfrag, wf[kc], acc, 0, 0, 0);
        }

        if (m < 2) {
            #pragma unroll
            for (int r = 0; r < 16; ++r)
                acc[r] += bias_lds[h * 32 + (r & 3) + 8 * (r >> 2) + 4 * hi];
        } else {
            const float bl = bias_lds[h * 32 + l31];
            #pragma unroll
            for (int r = 0; r < 16; ++r) acc[r] += bl;
            float cp = 0.f;
            #pragma unroll
            for (int r = 0; r < 16; ++r) cp += acc[r];
            cp += __shfl_xor(cp, 32);
            cpacc += cp;
        }

        uint wa0 = cvtpk(acc[0], acc[1]),   wa1 = cvtpk(acc[2], acc[3]);
        uint wb0 = cvtpk(acc[4], acc[5]),   wb1 = cvtpk(acc[6], acc[7]);
        uint wa2 = cvtpk(acc[8], acc[9]),   wa3 = cvtpk(acc[10], acc[11]);
        uint wb2 = cvtpk(acc[12], acc[13]), wb3 = cvtpk(acc[14], acc[15]);
        int2v s0 = __builtin_amdgcn_permlane32_swap((int)wa0, (int)wb0, false, false);
        int2v s1 = __builtin_amdgcn_permlane32_swap((int)wa1, (int)wb1, false, false);
        int2v s2 = __builtin_amdgcn_permlane32_swap((int)wa2, (int)wb2, false, false);
        int2v s3 = __builtin_amdgcn_permlane32_swap((int)wa3, (int)wb3, false, false);
        uint4 p0 = { (uint)s0[0], (uint)s1[0], (uint)s0[1], (uint)s1[1] };
        uint4 p1 = { (uint)s2[0], (uint)s3[0], (uint)s2[1], (uint)s3[1] };
        ushort* dst = yb + (((size_t)b_ * H + h) * 32 + t32) * 1024 + hi * 256 + l31 * 8;
        *(uint4*)dst = p0;
        *(uint4*)(dst + 512) = p1;
    }
    if (m == 2 && hi == 0)
        cpart[blockIdx.x * D + h * 32 + l31] = cpacc;
}

// ---------------------------------------------------------------------------
// K2: time+rel attention v4 — 1024 threads / 16 waves (4 waves/SIMD, 2x TLP).
// Phase 1: 16 waves x 4 chunks -> unnormalized weights streamed to LDS.
// Phase 2: wave pair (wd, 8+wd) splits the 66 MFMA slots 33/33 (balanced for
// every diagonal position), both keep accT/accR partials; combine via LDS.
// ---------------------------------------------------------------------------
__global__ __launch_bounds__(1024, 4) void timerel_mfma(
    const float* __restrict__ ts, const float* __restrict__ rel,
    const ushort* __restrict__ vtb, const float* __restrict__ cpart,
    const float* __restrict__ l1p, const float* __restrict__ l2p,
    float* __restrict__ out)
{
    __shared__ ushort wlds[66 * 512];          // 67.6 KB weight slots
    __shared__ float cbuf[8][64][17];          // 34.8 KB combine buffer
    __shared__ float rsum[2][16][32];
    __shared__ float normt[32], normr[32], nuni[32];

    const int b  = blockIdx.y;
    const int i0 = blockIdx.x * 32;
    const int ksd = i0 >> 4;                   // first diagonal chunk
    const int w = threadIdx.x >> 6, lane = threadIdx.x & 63;
    const int l31 = lane & 31, hi = lane >> 5;
    const int hi8 = hi * 8;
    const int i = i0 + l31;

    const float* tsrow  = ts  + ((size_t)b * S + i) * S + hi8;
    const float* relrow = rel + ((size_t)b * S + i) * S + hi8;

    // ---- phase 1: 4 chunks per wave, unnormalized weights -> LDS ----
    float st = 0.f, sr = 0.f;
    const int ks0 = w * 4;
    #pragma unroll
    for (int kk = 0; kk < 4; ++kk) {
        const int ks = ks0 + kk;
        const int js = ks * 16;
        ushort* slotT = wlds + ks * 512 + hi * 256 + l31 * 4;
        if (ks < ksd) {                        // pure past
            float tv[8];
            *(float4*)&tv[0] = *(const float4*)(tsrow + js);
            *(float4*)&tv[4] = *(const float4*)(tsrow + js + 4);
            uint wp[4];
            #pragma unroll
            for (int q = 0; q < 4; ++q) {
                float w0 = __expf(__expf(-fabsf(tv[2 * q])));
                float w1 = __expf(__expf(-fabsf(tv[2 * q + 1])));
                st += w0 + w1;
                wp[q] = cvtpk(w0, w1);
            }
            uint2 v0; v0.x = wp[0]; v0.y = wp[1];
            uint2 v1; v1.x = wp[2]; v1.y = wp[3];
            *(uint2*)slotT         = v0;
            *(uint2*)(slotT + 128) = v1;
        } else if (ks > ksd + 1) {             // pure future
            float rv[8];
            *(float4*)&rv[0] = *(const float4*)(relrow + js);
            *(float4*)&rv[4] = *(const float4*)(relrow + js + 4);
            uint wp[4];
            #pragma unroll
            for (int q = 0; q < 4; ++q) {
                float r0 = rv[2 * q], r1 = rv[2 * q + 1];
                float w0 = (r0 != 0.f) ? __expf(r0) : 0.f;
                float w1 = (r1 != 0.f) ? __expf(r1) : 0.f;
                sr += w0 + w1;
                wp[q] = cvtpk(w0, w1);
            }
            uint2 v0; v0.x = wp[0]; v0.y = wp[1];
            uint2 v1; v1.x = wp[2]; v1.y = wp[3];
            *(uint2*)slotT         = v0;
            *(uint2*)(slotT + 128) = v1;
        } else {                               // diagonal (mixed) chunk
            float tv[8], rv[8];
            *(float4*)&tv[0] = *(const float4*)(tsrow + js);
            *(float4*)&tv[4] = *(const float4*)(tsrow + js + 4);
            *(float4*)&rv[0] = *(const float4*)(relrow + js);
            *(float4*)&rv[4] = *(const float4*)(relrow + js + 4);
            uint wpT[4], wpR[4];
            #pragma unroll
            for (int q = 0; q < 4; ++q) {
                const int j0 = js + hi8 + 2 * q;
                const bool p0 = (j0     <= i), p1 = (j0 + 1 <= i);
                float t0 = __expf(__expf(-fabsf(tv[2 * q])));
                float t1 = __expf(__expf(-fabsf(tv[2 * q + 1])));
                float r0 = (rv[2 * q]     != 0.f) ? __expf(rv[2 * q])     : 0.f;
                float r1 = (rv[2 * q + 1] != 0.f) ? __expf(rv[2 * q + 1]) : 0.f;
                float wT0 = p0 ? t0 : 0.f, wT1 = p1 ? t1 : 0.f;
                float wR0 = p0 ? 0.f : r0, wR1 = p1 ? 0.f : r1;
                st += wT0 + wT1; sr += wR0 + wR1;
                wpT[q] = cvtpk(wT0, wT1);
                wpR[q] = cvtpk(wR0, wR1);
            }
            uint2 t0v; t0v.x = wpT[0]; t0v.y = wpT[1];
            uint2 t1v; t1v.x = wpT[2]; t1v.y = wpT[3];
            *(uint2*)slotT         = t0v;
            *(uint2*)(slotT + 128) = t1v;
            ushort* slotR = wlds + (64 + (ks - ksd)) * 512 + hi * 256 + l31 * 4;
            uint2 r0v; r0v.x = wpR[0]; r0v.y = wpR[1];
            uint2 r1v; r1v.x = wpR[2]; r1v.y = wpR[3];
            *(uint2*)slotR         = r0v;
            *(uint2*)(slotR + 128) = r1v;
        }
    }

    st += __shfl_xor(st, 32);
    sr += __shfl_xor(sr, 32);
    if (hi == 0) { rsum[0][w][l31] = st; rsum[1][w][l31] = sr; }
    __syncthreads();

    if (threadIdx.x < 32) {
        const int r = threadIdx.x;
        float stt = 0.f, srt = 0.f;
        #pragma unroll
        for (int q = 0; q < 16; ++q) { stt += rsum[0][q][r]; srt += rsum[1][q][r]; }
        const float l1 = l1p[0], l2 = l2p[0];
        normt[r] = (1.f - l1) * l2 / stt;
        normr[r] = (srt > 0.5f) ? (l1 / srt) : 0.f;
        nuni[r]  = (srt > 0.5f) ? 0.f : (l1 / (float)S);
    }
    __syncthreads();

    // ---- phase 2: wave pair splits 66 slots 33/33 ----
    const int wd = w & 7, upper = w >> 3;      // d-chunk, half selector
    const ushort* vtbase = vtb + ((size_t)b * 8 + wd) * 32768 + hi * 256 + l31 * 8;
    f32x16 accT, accR;
    #pragma unroll
    for (int r = 0; r < 16; ++r) { accT[r] = 0.f; accR[r] = 0.f; }

    const int s_begin = upper ? 33 : 0;
    const int s_end   = upper ? 66 : 33;
    for (int s = s_begin; s < s_end; ++s) {
        const int vch = (s < 64) ? s : (ksd + (s - 64));
        const ushort* rb = wlds + s * 512 + hi * 256 + l31 * 4;
        uint2 lo = *(const uint2*)rb;
        uint2 hj = *(const uint2*)(rb + 128);
        uint4 aw = { lo.x, lo.y, hj.x, hj.y };
        bf16x8 afrag = __builtin_bit_cast(bf16x8, aw);
        bf16x8 vf = *(const bf16x8*)(vtbase + (size_t)vch * 512);
        const bool isT = (s < 64) && (s <= ksd + 1);
        if (isT) accT = __builtin_amdgcn_mfma_f32_32x32x16_bf16(afrag, vf, accT, 0, 0, 0);
        else     accR = __builtin_amdgcn_mfma_f32_32x32x16_bf16(afrag, vf, accR, 0, 0, 0);
    }
    __syncthreads();                           // wlds reads done, cbuf safe

    if (upper) {
        float* cb = &cbuf[wd][lane][0];
        #pragma unroll
        for (int r = 0; r < 16; ++r) {
            const int row = (r & 3) + 8 * (r >> 2) + 4 * hi;
            cb[r] = accT[r] * normt[row] + accR[r] * normr[row];
        }
    }
    __syncthreads();

    if (!upper) {
        const int d = wd * 32 + l31;
        float cv = 0.f;
        if (i0 == S - 32) {
            #pragma unroll
            for (int p_ = 0; p_ < 16; ++p_)
                cv += cpart[(b * 16 + p_) * D + d];
        }
        const float* cb = &cbuf[wd][lane][0];
        float* obase = out + ((size_t)b * S + i0) * D + d;
        #pragma unroll
        for (int r = 0; r < 16; ++r) {
            const int row = (r & 3) + 8 * (r >> 2) + 4 * hi;
            obase[(size_t)row * D] =
                accT[r] * normt[row] + accR[r] * normr[row] + cb[r] + nuni[row] * cv;
        }
    }
}

// ---------------------------------------------------------------------------
// K3: MFMA flash attention (R9 form).
// ---------------------------------------------------------------------------
#define LOADKV(K0, K1, V0, V1, KT) do { \
    const ushort* kp_ = kbase + (size_t)(KT) * 1024; \
    const ushort* vp_ = vbase + (size_t)(KT) * 1024; \
    K0 = *(const bf16x8*)kp_;        K1 = *(const bf16x8*)(kp_ + 512); \
    V0 = *(const bf16x8*)vp_;        V1 = *(const bf16x8*)(vp_ + 512); \
} while (0)

#define TILE_COMPUTE(K0, K1, V0, V1, ISDIAG) do { \
    f32x16 stv; \
    _Pragma("unroll") for (int r = 0; r < 16; ++r) stv[r] = 0.f; \
    stv = __builtin_amdgcn_mfma_f32_32x32x16_bf16(K0, qf0, stv, 0, 0, 0); \
    stv = __builtin_amdgcn_mfma_f32_32x32x16_bf16(K1, qf1, stv, 0, 0, 0); \
    if (ISDIAG) { \
        _Pragma("unroll") for (int r = 0; r < 16; ++r) \
            if (((r & 3) + 8 * (r >> 2) + 4 * hi) > l31) stv[r] = -1e30f; \
    } \
    float p[16]; \
    _Pragma("unroll") for (int r = 0; r < 16; ++r) { p[r] = exp2f(stv[r]); lacc += p[r]; } \
    uint wa0 = cvtpk(p[0], p[1]),   wa1 = cvtpk(p[2], p[3]); \
    uint wb0 = cvtpk(p[4], p[5]),   wb1 = cvtpk(p[6], p[7]); \
    uint wa2 = cvtpk(p[8], p[9]),   wa3 = cvtpk(p[10], p[11]); \
    uint wb2 = cvtpk(p[12], p[13]), wb3 = cvtpk(p[14], p[15]); \
    int2v s0 = __builtin_amdgcn_permlane32_swap((int)wa0, (int)wb0, false, false); \
    int2v s1 = __builtin_amdgcn_permlane32_swap((int)wa1, (int)wb1, false, false); \
    int2v s2 = __builtin_amdgcn_permlane32_swap((int)wa2, (int)wb2, false, false); \
    int2v s3 = __builtin_amdgcn_permlane32_swap((int)wa3, (int)wb3, false, false); \
    uint4 pa0i = { (uint)s0[0], (uint)s1[0], (uint)s0[1], (uint)s1[1] }; \
    uint4 pa1i = { (uint)s2[0], (uint)s3[0], (uint)s2[1], (uint)s3[1] }; \
    bf16x8 pa0 = __builtin_bit_cast(bf16x8, pa0i); \
    bf16x8 pa1 = __builtin_bit_cast(bf16x8, pa1i); \
    ot = __builtin_amdgcn_mfma_f32_32x32x16_bf16(V0, pa0, ot, 0, 0, 0); \
    ot = __builtin_amdgcn_mfma_f32_32x32x16_bf16(V1, pa1, ot, 0, 0, 0); \
} while (0)

__global__ __launch_bounds__(512, 4) void flash_mfma(
    const ushort* __restrict__ qb, const ushort* __restrict__ kb,
    const ushort* __restrict__ vtb, const float* __restrict__ l1p,
    const float* __restrict__ l2p, float* __restrict__ out)
{
    __shared__ float mbuf[4][64][18];
    __shared__ float lds_t[4][32 * 33];
    const int id = blockIdx.x;
    const int halfg = id >> 8, rr_ = id & 255;
    const int qraw = rr_ >> 5;
    const int qblk = halfg ? (7 - qraw) : qraw;
    const int bh = (rr_ & 31) | (halfg << 5);
    const int b = bh >> 3, h = bh & 7;
    const int w = threadIdx.x >> 6, lane = threadIdx.x & 63;
    const int sub = w & 3, half = w >> 2;
    const int l31 = lane & 31, hi = lane >> 5;
    const int qt = qblk * 4 + sub;
    const float c_p = (1.f - l1p[0]) * (1.f - l2p[0]);

    const ushort* qp_ = qb + ((size_t)bh * 32 + qt) * 1024 + hi * 256 + l31 * 8;
    const bf16x8 qf0 = *(const bf16x8*)qp_;
    const bf16x8 qf1 = *(const bf16x8*)(qp_ + 512);
    const ushort* kbase = kb  + (size_t)bh * 32768 + hi * 256 + l31 * 8;
    const ushort* vbase = vtb + (size_t)bh * 32768 + hi * 256 + l31 * 8;

    f32x16 ot;
    #pragma unroll
    for (int r = 0; r < 16; ++r) ot[r] = 0.f;
    float lacc = 0.f;

    const int nlo = (qt + 1) >> 1;
    const int klo = half ? nlo : 0;
    const int khi = half ? qt : (nlo - 1);

    if (klo <= khi) {
        bf16x8 kA0, kA1, vA0, vA1, kB0, kB1, vB0, vB1;
        LOADKV(kA0, kA1, vA0, vA1, klo);
        int kt = klo;
        for (;;) {
            if (kt + 1 <= khi) LOADKV(kB0, kB1, vB0, vB1, kt + 1);
            TILE_COMPUTE(kA0, kA1, vA0, vA1, kt == qt);
            if (++kt > khi) break;
            if (kt + 1 <= khi) LOADKV(kA0, kA1, vA0, vA1, kt + 1);
            TILE_COMPUTE(kB0, kB1, vB0, vB1, kt == qt);
            if (++kt > khi) break;
        }
    }

    if (half == 1) {
        float* mb = &mbuf[sub][lane][0];
        #pragma unroll
        for (int r = 0; r < 16; r += 4)
            *(float4*)&mb[r] = make_float4(ot[r], ot[r+1], ot[r+2], ot[r+3]);
        mb[16] = lacc;
    }
    __syncthreads();

    if (half == 0) {
        const float* mb = &mbuf[sub][lane][0];
        #pragma unroll
        for (int r = 0; r < 16; ++r) ot[r] += mb[r];
        lacc += mb[16];
        const float lrun = lacc + xswap32f(lacc, hi);
        const float inv = c_p / lrun;
        float* lt = lds_t[sub];
        #pragma unroll
        for (int r = 0; r < 16; ++r) {
            const int d = (r & 3) + 8 * (r >> 2) + 4 * hi;
            lt[l31 * 33 + d] = ot[r] * inv;
        }
    }
    __syncthreads();
    if (half == 0) {
        const int q0w = qt * 32;
        const float* lt = lds_t[sub];
        #pragma unroll
        for (int rr = 0; rr < 4; ++rr) {
            const int ql = rr * 8 + (lane >> 3);
            const int d0 = (lane & 7) * 4;
            const float* lp = &lt[ql * 33 + d0];
            float* op = out + ((size_t)b * S + q0w + ql) * D + h * 32 + d0;
            float4 cur = *(const float4*)op;
            cur.x += lp[0]; cur.y += lp[1]; cur.z += lp[2]; cur.w += lp[3];
            *(float4*)op = cur;
        }
    }
}

// ---------------------------------------------------------------------------
extern "C" void kernel_launch(void* const* d_in, const int* in_sizes, int n_in,
                              void* d_out, int out_size, void* d_ws, size_t ws_size,
                              hipStream_t stream)
{
    (void)in_sizes; (void)n_in; (void)out_size; (void)ws_size;
    const float* query = (const float*)d_in[0];
    const float* key_  = (const float*)d_in[1];
    const float* value = (const float*)d_in[2];
    const float* rel   = (const float*)d_in[3];
    const float* tsp   = (const float*)d_in[4];
    const float* l1p   = (const float*)d_in[5];
    const float* l2p   = (const float*)d_in[6];
    const float* Wq    = (const float*)d_in[7];
    const float* bq    = (const float*)d_in[8];
    const float* Wk    = (const float*)d_in[9];
    const float* bk    = (const float*)d_in[10];
    const float* Wv    = (const float*)d_in[11];
    const float* bv    = (const float*)d_in[12];
    float* out = (float*)d_out;

    ushort* qbuf  = (ushort*)d_ws;
    ushort* kbuf  = (ushort*)((char*)d_ws + (4u  << 20));
    ushort* vtbuf = (ushort*)((char*)d_ws + (8u  << 20));
    float*  cpart = (float*)((char*)d_ws + (12u << 20));

    const float qscale = 1.4426950408889634f * 0.17677669529663687f;

    proj_mfma<<<dim3(128, 3), 512, 0, stream>>>(
        query, key_, value, Wq, Wk, Wv, bq, bk, bv, qscale,
        qbuf, kbuf, vtbuf, cpart);

    timerel_mfma<<<dim3(S / 32, B), 1024, 0, stream>>>(
        tsp, rel, vtbuf, cpart, l1p, l2p, out);

    flash_mfma<<<512, 512, 0, stream>>>(qbuf, kbuf, vtbuf, l1p, l2p, out);
}

// Round 15
// 64.438 us; speedup vs baseline: 1.0372x; 1.0372x over previous
//
#include <hip/hip_runtime.h>
#include <math.h>

constexpr int B = 8, S = 1024, D = 256, H = 8, HD = 32;

typedef __attribute__((ext_vector_type(8))) short bf16x8;
typedef __attribute__((ext_vector_type(16))) float f32x16;
typedef __attribute__((ext_vector_type(2)))  int  int2v;

__device__ __forceinline__ uint cvtpk(float a, float b) {
    uint r;
    asm("v_cvt_pk_bf16_f32 %0, %1, %2" : "=v"(r) : "v"(a), "v"(b));
    return r;
}
__device__ __forceinline__ float xswap32f(float v, int hi) {
    int2v t = __builtin_amdgcn_permlane32_swap(__float_as_int(v), __float_as_int(v), false, false);
    return __int_as_float(hi ? t[0] : t[1]);
}

// ---------------------------------------------------------------------------
// K1: fused MFMA projection (R9 form).
// ---------------------------------------------------------------------------
__global__ __launch_bounds__(512, 4) void proj_mfma(
    const float* __restrict__ query, const float* __restrict__ key_,
    const float* __restrict__ value,
    const float* __restrict__ Wq, const float* __restrict__ Wk,
    const float* __restrict__ Wv,
    const float* __restrict__ bq, const float* __restrict__ bk,
    const float* __restrict__ bv, float qscale,
    ushort* __restrict__ qbuf, ushort* __restrict__ kbuf,
    ushort* __restrict__ vtbuf, float* __restrict__ cpart)
{
    __shared__ ushort xf[8192];
    __shared__ float bias_lds[256];

    const int m = blockIdx.y;
    const int tid = threadIdx.x;
    const int w = tid >> 6, lane = tid & 63;
    const int l31 = lane & 31, hi = lane >> 5;
    const int h = w;

    const float* xsrc = (m == 0) ? query : (m == 1) ? key_ : value;
    const float* Wsrc = (m == 0) ? Wq : (m == 1) ? Wk : Wv;
    const float* bsrc = (m == 0) ? bq : (m == 1) ? bk : bv;
    ushort* yb = (m == 0) ? qbuf : (m == 1) ? kbuf : vtbuf;
    const float wscale = (m == 0) ? qscale : 1.0f;

    if (tid < 256) bias_lds[tid] = bsrc[tid] * wscale;

    bf16x8 wf[16];
    {
        const float* wrow = Wsrc + ((size_t)(h * 32 + l31)) * 256 + hi * 8;
        #pragma unroll
        for (int kc = 0; kc < 16; ++kc) {
            float4 a = *(const float4*)(wrow + kc * 16);
            float4 b = *(const float4*)(wrow + kc * 16 + 4);
            uint4 p;
            p.x = cvtpk(a.x * wscale, a.y * wscale);
            p.y = cvtpk(a.z * wscale, a.w * wscale);
            p.z = cvtpk(b.x * wscale, b.y * wscale);
            p.w = cvtpk(b.z * wscale, b.w * wscale);
            wf[kc] = __builtin_bit_cast(bf16x8, p);
        }
    }

    const int sst = tid & 31, skc = tid >> 5;
    float cpacc = 0.f;

    for (int it = 0; it < 2; ++it) {
        const int stile = blockIdx.x * 2 + it;
        const int b_ = stile >> 5, t32 = stile & 31;

        __syncthreads();
        {
            const float* xrow = xsrc + ((size_t)(stile * 32 + sst)) * 256 + skc * 16;
            float4 a0 = *(const float4*)(xrow + 0);
            float4 a1 = *(const float4*)(xrow + 4);
            float4 a2 = *(const float4*)(xrow + 8);
            float4 a3 = *(const float4*)(xrow + 12);
            uint2 w01 = { cvtpk(a0.x, a0.y), cvtpk(a0.z, a0.w) };
            uint2 w23 = { cvtpk(a1.x, a1.y), cvtpk(a1.z, a1.w) };
            uint2 w45 = { cvtpk(a2.x, a2.y), cvtpk(a2.z, a2.w) };
            uint2 w67 = { cvtpk(a3.x, a3.y), cvtpk(a3.z, a3.w) };
            ushort* base = xf + skc * 512 + sst * 4;
            *(uint2*)(base +   0) = w01;
            *(uint2*)(base + 128) = w23;
            *(uint2*)(base + 256) = w45;
            *(uint2*)(base + 384) = w67;
        }
        __syncthreads();

        f32x16 acc;
        #pragma unroll
        for (int r = 0; r < 16; ++r) acc[r] = 0.f;
        #pragma unroll
        for (int kc = 0; kc < 16; ++kc) {
            const ushort* rb = xf + kc * 512 + hi * 256 + l31 * 4;
            uint2 lo = *(const uint2*)rb;
            uint2 hj = *(const uint2*)(rb + 128);
            uint4 xw = { lo.x, lo.y, hj.x, hj.y };
            bf16x8 xfrag = __builtin_bit_cast(bf16x8, xw);
            if (m < 2)
                acc = __builtin_amdgcn_mfma_f32_32x32x16_bf16(wf[kc], xfrag, acc, 0, 0, 0);
            else
                acc = __builtin_amdgcn_mfma_f32_32x32x16_bf16(xfrag, wf[kc], acc, 0, 0, 0);
        }

        if (m < 2) {
            #pragma unroll
            for (int r = 0; r < 16; ++r)
                acc[r] += bias_lds[h * 32 + (r & 3) + 8 * (r >> 2) + 4 * hi];
        } else {
            const float bl = bias_lds[h * 32 + l31];
            #pragma unroll
            for (int r = 0; r < 16; ++r) acc[r] += bl;
            float cp = 0.f;
            #pragma unroll
            for (int r = 0; r < 16; ++r) cp += acc[r];
            cp += __shfl_xor(cp, 32);
            cpacc += cp;
        }

        uint wa0 = cvtpk(acc[0], acc[1]),   wa1 = cvtpk(acc[2], acc[3]);
        uint wb0 = cvtpk(acc[4], acc[5]),   wb1 = cvtpk(acc[6], acc[7]);
        uint wa2 = cvtpk(acc[8], acc[9]),   wa3 = cvtpk(acc[10], acc[11]);
        uint wb2 = cvtpk(acc[12], acc[13]), wb3 = cvtpk(acc[14], acc[15]);
        int2v s0 = __builtin_amdgcn_permlane32_swap((int)wa0, (int)wb0, false, false);
        int2v s1 = __builtin_amdgcn_permlane32_swap((int)wa1, (int)wb1, false, false);
        int2v s2 = __builtin_amdgcn_permlane32_swap((int)wa2, (int)wb2, false, false);
        int2v s3 = __builtin_amdgcn_permlane32_swap((int)wa3, (int)wb3, false, false);
        uint4 p0 = { (uint)s0[0], (uint)s1[0], (uint)s0[1], (uint)s1[1] };
        uint4 p1 = { (uint)s2[0], (uint)s3[0], (uint)s2[1], (uint)s3[1] };
        ushort* dst = yb + (((size_t)b_ * H + h) * 32 + t32) * 1024 + hi * 256 + l31 * 8;
        *(uint4*)dst = p0;
        *(uint4*)(dst + 512) = p1;
    }
    if (m == 2 && hi == 0)
        cpart[blockIdx.x * D + h * 32 + l31] = cpacc;
}

// ---------------------------------------------------------------------------
// K2: time+rel v5 — COALESCED phase 1 (lane = contiguous cols, 1-2 lines per
// wave-load vs 32 before) + row-swizzled fragment LDS (involution
// row ^= jh|hig<<1|(ks&7)<<2 on both sides). Wave owns 4 whole rows; paired
// butterflies for row sums; norm folded pre-pack; phase 2 = R9 single chain.
// ---------------------------------------------------------------------------
__global__ __launch_bounds__(512, 4) void timerel_mfma(
    const float* __restrict__ ts, const float* __restrict__ rel,
    const ushort* __restrict__ vtb, const float* __restrict__ cpart,
    const float* __restrict__ l1p, const float* __restrict__ l2p,
    float* __restrict__ out)
{
    __shared__ ushort wlds[64 * 512];      // 64KB swizzled fragment slots
    __shared__ float nuni[32];

    const int b  = blockIdx.y;
    const int i0 = blockIdx.x * 32;
    const int w = threadIdx.x >> 6, lane = threadIdx.x & 63;
    const int l31 = lane & 31, hi = lane >> 5;
    const float l1 = l1p[0], l2 = l2p[0];

    // lane-constant write-slot fields (column block jb = seg*256 + lane*4)
    const int hig_w = (lane >> 1) & 1, jh_w = lane & 1;
    const int ksl_lo = lane >> 2;          // + seg*16

    for (int pp = 0; pp < 2; ++pp) {
        float wv[2][4][4];
        float stp[2] = { 0.f, 0.f }, srp[2] = { 0.f, 0.f };
        #pragma unroll
        for (int rr = 0; rr < 2; ++rr) {
            const int row = w * 4 + pp * 2 + rr;
            const int i = i0 + row;
            const float* tsrow  = ts  + ((size_t)b * S + i) * S;
            const float* relrow = rel + ((size_t)b * S + i) * S;
            #pragma unroll
            for (int seg = 0; seg < 4; ++seg) {
                const int jb = seg * 256 + lane * 4;
                if (seg * 256 + 255 <= i) {          // segment all past
                    float4 t4 = *(const float4*)(tsrow + jb);
                    const float te[4] = { t4.x, t4.y, t4.z, t4.w };
                    #pragma unroll
                    for (int e = 0; e < 4; ++e) {
                        float v = __expf(__expf(-fabsf(te[e])));
                        stp[rr] += v; wv[rr][seg][e] = v;
                    }
                } else if (seg * 256 > i) {          // segment all future
                    float4 r4 = *(const float4*)(relrow + jb);
                    const float re[4] = { r4.x, r4.y, r4.z, r4.w };
                    #pragma unroll
                    for (int e = 0; e < 4; ++e) {
                        float v = (re[e] != 0.f) ? __expf(re[e]) : 0.f;
                        srp[rr] += v; wv[rr][seg][e] = v;
                    }
                } else {                             // mixed segment
                    float4 t4 = *(const float4*)(tsrow + jb);
                    float4 r4 = *(const float4*)(relrow + jb);
                    const float te[4] = { t4.x, t4.y, t4.z, t4.w };
                    const float re[4] = { r4.x, r4.y, r4.z, r4.w };
                    #pragma unroll
                    for (int e = 0; e < 4; ++e) {
                        float v;
                        if (jb + e <= i) { v = __expf(__expf(-fabsf(te[e]))); stp[rr] += v; }
                        else             { v = (re[e] != 0.f) ? __expf(re[e]) : 0.f; srp[rr] += v; }
                        wv[rr][seg][e] = v;
                    }
                }
            }
        }
        // paired 64-lane butterflies (ILP across the 4 independent sums)
        #pragma unroll
        for (int off = 1; off < 64; off <<= 1) {
            stp[0] += __shfl_xor(stp[0], off);
            srp[0] += __shfl_xor(srp[0], off);
            stp[1] += __shfl_xor(stp[1], off);
            srp[1] += __shfl_xor(srp[1], off);
        }
        #pragma unroll
        for (int rr = 0; rr < 2; ++rr) {
            const int row = w * 4 + pp * 2 + rr;
            const int i = i0 + row;
            const float nt = (1.f - l1) * l2 / stp[rr];
            const float nr = (srp[rr] > 0.5f) ? (l1 / srp[rr]) : 0.f;
            if (lane == 0) nuni[row] = (srp[rr] > 0.5f) ? 0.f : (l1 / (float)S);
            #pragma unroll
            for (int seg = 0; seg < 4; ++seg) {
                const int jb = seg * 256 + lane * 4;
                float a0 = wv[rr][seg][0] * ((jb     <= i) ? nt : nr);
                float a1 = wv[rr][seg][1] * ((jb + 1 <= i) ? nt : nr);
                float a2 = wv[rr][seg][2] * ((jb + 2 <= i) ? nt : nr);
                float a3 = wv[rr][seg][3] * ((jb + 3 <= i) ? nt : nr);
                uint2 pk; pk.x = cvtpk(a0, a1); pk.y = cvtpk(a2, a3);
                const int ksl = seg * 16 + ksl_lo;
                const int xorv = jh_w | (hig_w << 1) | ((ksl & 7) << 2);
                char* dst = (char*)wlds + ksl * 1024 + hig_w * 512 + jh_w * 256
                            + ((row ^ xorv) & 31) * 8;
                *(uint2*)dst = pk;
            }
        }
    }
    __syncthreads();

    // ---- phase 2: single MFMA chain per wave over its 32-d chunk ----
    const ushort* vtbase = vtb + ((size_t)b * 8 + w) * 32768 + hi * 256 + l31 * 8;
    f32x16 acc;
    #pragma unroll
    for (int r = 0; r < 16; ++r) acc[r] = 0.f;
    #pragma unroll 4
    for (int ks = 0; ks < 64; ++ks) {
        const int x0 = 0 | (hi << 1) | ((ks & 7) << 2);
        const int x1 = 1 | (hi << 1) | ((ks & 7) << 2);
        const char* base = (const char*)wlds + ks * 1024 + hi * 512;
        uint2 lo = *(const uint2*)(base +       ((l31 ^ x0) & 31) * 8);
        uint2 hj = *(const uint2*)(base + 256 + ((l31 ^ x1) & 31) * 8);
        uint4 aw = { lo.x, lo.y, hj.x, hj.y };
        bf16x8 afrag = __builtin_bit_cast(bf16x8, aw);
        bf16x8 vf = *(const bf16x8*)(vtbase + (size_t)ks * 512);
        acc = __builtin_amdgcn_mfma_f32_32x32x16_bf16(afrag, vf, acc, 0, 0, 0);
    }

    const int d = w * 32 + l31;
    float cv = 0.f;
    if (i0 == S - 32) {
        #pragma unroll
        for (int p_ = 0; p_ < 16; ++p_)
            cv += cpart[(b * 16 + p_) * D + d];
    }
    float* obase = out + ((size_t)b * S + i0) * D + d;
    #pragma unroll
    for (int r = 0; r < 16; ++r) {
        const int row = (r & 3) + 8 * (r >> 2) + 4 * hi;
        obase[(size_t)row * D] = acc[r] + nuni[row] * cv;
    }
}

// ---------------------------------------------------------------------------
// K3: MFMA flash attention (R9 form).
// ---------------------------------------------------------------------------
#define LOADKV(K0, K1, V0, V1, KT) do { \
    const ushort* kp_ = kbase + (size_t)(KT) * 1024; \
    const ushort* vp_ = vbase + (size_t)(KT) * 1024; \
    K0 = *(const bf16x8*)kp_;        K1 = *(const bf16x8*)(kp_ + 512); \
    V0 = *(const bf16x8*)vp_;        V1 = *(const bf16x8*)(vp_ + 512); \
} while (0)

#define TILE_COMPUTE(K0, K1, V0, V1, ISDIAG) do { \
    f32x16 stv; \
    _Pragma("unroll") for (int r = 0; r < 16; ++r) stv[r] = 0.f; \
    stv = __builtin_amdgcn_mfma_f32_32x32x16_bf16(K0, qf0, stv, 0, 0, 0); \
    stv = __builtin_amdgcn_mfma_f32_32x32x16_bf16(K1, qf1, stv, 0, 0, 0); \
    if (ISDIAG) { \
        _Pragma("unroll") for (int r = 0; r < 16; ++r) \
            if (((r & 3) + 8 * (r >> 2) + 4 * hi) > l31) stv[r] = -1e30f; \
    } \
    float p[16]; \
    _Pragma("unroll") for (int r = 0; r < 16; ++r) { p[r] = exp2f(stv[r]); lacc += p[r]; } \
    uint wa0 = cvtpk(p[0], p[1]),   wa1 = cvtpk(p[2], p[3]); \
    uint wb0 = cvtpk(p[4], p[5]),   wb1 = cvtpk(p[6], p[7]); \
    uint wa2 = cvtpk(p[8], p[9]),   wa3 = cvtpk(p[10], p[11]); \
    uint wb2 = cvtpk(p[12], p[13]), wb3 = cvtpk(p[14], p[15]); \
    int2v s0 = __builtin_amdgcn_permlane32_swap((int)wa0, (int)wb0, false, false); \
    int2v s1 = __builtin_amdgcn_permlane32_swap((int)wa1, (int)wb1, false, false); \
    int2v s2 = __builtin_amdgcn_permlane32_swap((int)wa2, (int)wb2, false, false); \
    int2v s3 = __builtin_amdgcn_permlane32_swap((int)wa3, (int)wb3, false, false); \
    uint4 pa0i = { (uint)s0[0], (uint)s1[0], (uint)s0[1], (uint)s1[1] }; \
    uint4 pa1i = { (uint)s2[0], (uint)s3[0], (uint)s2[1], (uint)s3[1] }; \
    bf16x8 pa0 = __builtin_bit_cast(bf16x8, pa0i); \
    bf16x8 pa1 = __builtin_bit_cast(bf16x8, pa1i); \
    ot = __builtin_amdgcn_mfma_f32_32x32x16_bf16(V0, pa0, ot, 0, 0, 0); \
    ot = __builtin_amdgcn_mfma_f32_32x32x16_bf16(V1, pa1, ot, 0, 0, 0); \
} while (0)

__global__ __launch_bounds__(512, 4) void flash_mfma(
    const ushort* __restrict__ qb, const ushort* __restrict__ kb,
    const ushort* __restrict__ vtb, const float* __restrict__ l1p,
    const float* __restrict__ l2p, float* __restrict__ out)
{
    __shared__ float mbuf[4][64][18];
    __shared__ float lds_t[4][32 * 33];
    const int id = blockIdx.x;
    const int halfg = id >> 8, rr_ = id & 255;
    const int qraw = rr_ >> 5;
    const int qblk = halfg ? (7 - qraw) : qraw;
    const int bh = (rr_ & 31) | (halfg << 5);
    const int b = bh >> 3, h = bh & 7;
    const int w = threadIdx.x >> 6, lane = threadIdx.x & 63;
    const int sub = w & 3, half = w >> 2;
    const int l31 = lane & 31, hi = lane >> 5;
    const int qt = qblk * 4 + sub;
    const float c_p = (1.f - l1p[0]) * (1.f - l2p[0]);

    const ushort* qp_ = qb + ((size_t)bh * 32 + qt) * 1024 + hi * 256 + l31 * 8;
    const bf16x8 qf0 = *(const bf16x8*)qp_;
    const bf16x8 qf1 = *(const bf16x8*)(qp_ + 512);
    const ushort* kbase = kb  + (size_t)bh * 32768 + hi * 256 + l31 * 8;
    const ushort* vbase = vtb + (size_t)bh * 32768 + hi * 256 + l31 * 8;

    f32x16 ot;
    #pragma unroll
    for (int r = 0; r < 16; ++r) ot[r] = 0.f;
    float lacc = 0.f;

    const int nlo = (qt + 1) >> 1;
    const int klo = half ? nlo : 0;
    const int khi = half ? qt : (nlo - 1);

    if (klo <= khi) {
        bf16x8 kA0, kA1, vA0, vA1, kB0, kB1, vB0, vB1;
        LOADKV(kA0, kA1, vA0, vA1, klo);
        int kt = klo;
        for (;;) {
            if (kt + 1 <= khi) LOADKV(kB0, kB1, vB0, vB1, kt + 1);
            TILE_COMPUTE(kA0, kA1, vA0, vA1, kt == qt);
            if (++kt > khi) break;
            if (kt + 1 <= khi) LOADKV(kA0, kA1, vA0, vA1, kt + 1);
            TILE_COMPUTE(kB0, kB1, vB0, vB1, kt == qt);
            if (++kt > khi) break;
        }
    }

    if (half == 1) {
        float* mb = &mbuf[sub][lane][0];
        #pragma unroll
        for (int r = 0; r < 16; r += 4)
            *(float4*)&mb[r] = make_float4(ot[r], ot[r+1], ot[r+2], ot[r+3]);
        mb[16] = lacc;
    }
    __syncthreads();

    if (half == 0) {
        const float* mb = &mbuf[sub][lane][0];
        #pragma unroll
        for (int r = 0; r < 16; ++r) ot[r] += mb[r];
        lacc += mb[16];
        const float lrun = lacc + xswap32f(lacc, hi);
        const float inv = c_p / lrun;
        float* lt = lds_t[sub];
        #pragma unroll
        for (int r = 0; r < 16; ++r) {
            const int d = (r & 3) + 8 * (r >> 2) + 4 * hi;
            lt[l31 * 33 + d] = ot[r] * inv;
        }
    }
    __syncthreads();
    if (half == 0) {
        const int q0w = qt * 32;
        const float* lt = lds_t[sub];
        #pragma unroll
        for (int rr = 0; rr < 4; ++rr) {
            const int ql = rr * 8 + (lane >> 3);
            const int d0 = (lane & 7) * 4;
            const float* lp = &lt[ql * 33 + d0];
            float* op = out + ((size_t)b * S + q0w + ql) * D + h * 32 + d0;
            float4 cur = *(const float4*)op;
            cur.x += lp[0]; cur.y += lp[1]; cur.z += lp[2]; cur.w += lp[3];
            *(float4*)op = cur;
        }
    }
}

// ---------------------------------------------------------------------------
extern "C" void kernel_launch(void* const* d_in, const int* in_sizes, int n_in,
                              void* d_out, int out_size, void* d_ws, size_t ws_size,
                              hipStream_t stream)
{
    (void)in_sizes; (void)n_in; (void)out_size; (void)ws_size;
    const float* query = (const float*)d_in[0];
    const float* key_  = (const float*)d_in[1];
    const float* value = (const float*)d_in[2];
    const float* rel   = (const float*)d_in[3];
    const float* tsp   = (const float*)d_in[4];
    const float* l1p   = (const float*)d_in[5];
    const float* l2p   = (const float*)d_in[6];
    const float* Wq    = (const float*)d_in[7];
    const float* bq    = (const float*)d_in[8];
    const float* Wk    = (const float*)d_in[9];
    const float* bk    = (const float*)d_in[10];
    const float* Wv    = (const float*)d_in[11];
    const float* bv    = (const float*)d_in[12];
    float* out = (float*)d_out;

    ushort* qbuf  = (ushort*)d_ws;
    ushort* kbuf  = (ushort*)((char*)d_ws + (4u  << 20));
    ushort* vtbuf = (ushort*)((char*)d_ws + (8u  << 20));
    float*  cpart = (float*)((char*)d_ws + (12u << 20));

    const float qscale = 1.4426950408889634f * 0.17677669529663687f;

    proj_mfma<<<dim3(128, 3), 512, 0, stream>>>(
        query, key_, value, Wq, Wk, Wv, bq, bk, bv, qscale,
        qbuf, kbuf, vtbuf, cpart);

    timerel_mfma<<<dim3(S / 32, B), 512, 0, stream>>>(
        tsp, rel, vtbuf, cpart, l1p, l2p, out);

    flash_mfma<<<512, 512, 0, stream>>>(qbuf, kbuf, vtbuf, l1p, l2p, out);
}